// Round 13
// baseline (332.570 us; speedup 1.0000x reference)
//
#include <hip/hip_runtime.h>
#include <math.h>

// NoisyTopKRouter, round 13: per-wave LDS ring + provably-safe counted vmcnt.
//   r9 ablation: B-fetch latency is the binder. r12 (same mechanism) raced in the
//   tail because a fixed vmcnt(7) census broke when stages were skipped. Now the
//   invariant is local: at top of each step, outstanding = [B(s) x3 older, A(s) x4
//   newer] (order pinned by SB0 between BSTAGE and LOADA), so vmcnt(4) before the
//   ds_read ALWAYS guarantees B(s) landed - tails included. A-reg validity is the
//   compiler's own waitcnt job. lgkmcnt(0)+SB0 before slot reuse (rule 18).
//   Geometry: 8 waves = 8 n-tiles, MT=2, BM=32, grid 512, 4 waves/SIMD, barrier-free.
// Outputs (flat f32): gate_weights [N][64], top2 idx as float [N][2], logits [N][64].

typedef float   f32x4   __attribute__((ext_vector_type(4)));
typedef __bf16  bf16x8  __attribute__((ext_vector_type(8)));
typedef unsigned short ushort8 __attribute__((ext_vector_type(8)));

#define EE 64     // experts
#define E2 128    // gate+noise logit columns
#define BM 32     // tokens per block

__device__ __forceinline__ unsigned short bf16_rne(float f) {
    unsigned int u = __float_as_uint(f);
    u += 0x7fffu + ((u >> 16) & 1u);
    return (unsigned short)(u >> 16);
}
__device__ __forceinline__ float bf16_f32(unsigned short h) {
    return __uint_as_float(((unsigned int)h) << 16);
}
__device__ __forceinline__ void split3(float a, unsigned short& h1,
                                       unsigned short& h2, unsigned short& h3) {
    h1 = bf16_rne(a);
    float r  = a - bf16_f32(h1);     // exact
    h2 = bf16_rne(r);
    float r2 = r - bf16_f32(h2);     // exact
    h3 = bf16_rne(r2);
}

__device__ __forceinline__ void gload_lds16(const void* g, void* l) {
    __builtin_amdgcn_global_load_lds(
        (const __attribute__((address_space(1))) void*)g,
        (__attribute__((address_space(3))) void*)l, 16, 0, 0);
}

// ---- pre-kernel: pack W (gate cols 0..63, noise cols 64..127) into B-frag order.
// Fragment (16x16x32 bf16, verified): lane l holds col=l&15, k=(l>>4)*8+j.
// Packed ushort addr: ((ks*8 + nt)*3 + term)*512 + lane*8 + j   (ks = k/32)
__global__ __launch_bounds__(256) void pack_b(
    const float* __restrict__ wg, const float* __restrict__ wn,
    unsigned short* __restrict__ bp, int Hdim)
{
    int pair = blockIdx.x * 4 + (threadIdx.x >> 6);   // (ks, nt)
    int l    = threadIdx.x & 63;
    int ks   = pair >> 3;
    int nt   = pair & 7;
    int col  = nt * 16 + (l & 15);
    int k    = ks * 32 + ((l >> 4) * 8);
    const float* wrow = (col < EE) ? (wg + (size_t)col * Hdim)
                                   : (wn + (size_t)(col - EE) * Hdim);
    float4 v0 = *reinterpret_cast<const float4*>(wrow + k);
    float4 v1 = *reinterpret_cast<const float4*>(wrow + k + 4);
    float vals[8] = {v0.x, v0.y, v0.z, v0.w, v1.x, v1.y, v1.z, v1.w};
    ushort8 t1, t2, t3;
    #pragma unroll
    for (int j = 0; j < 8; ++j) {
        unsigned short a, b, c;
        split3(vals[j], a, b, c);
        t1[j] = a; t2[j] = b; t3[j] = c;
    }
    size_t base = ((size_t)(ks * 8 + nt) * 3) * 512 + (size_t)l * 8;
    *reinterpret_cast<ushort8*>(bp + base        ) = t1;
    *reinterpret_cast<ushort8*>(bp + base + 512  ) = t2;
    *reinterpret_cast<ushort8*>(bp + base + 1024 ) = t3;
}

#define MFMA(a, b, c) __builtin_amdgcn_mfma_f32_16x16x32_bf16((a), (b), (c), 0, 0, 0)
#define SB0() __builtin_amdgcn_sched_barrier(0)
#define WAIT_VM4()  do { asm volatile("s_waitcnt vmcnt(4)" ::: "memory"); SB0(); } while (0)
#define WAIT_LGKM() do { asm volatile("s_waitcnt lgkmcnt(0)" ::: "memory"); SB0(); } while (0)

union ShMem {
    unsigned char ring[8][2][3072];      // [wave][slot][3 frags x 1KB] = 48 KB
    float Lred[BM][E2 + 5];              // 17 KB, reused after the main loop
};

__global__ __launch_bounds__(512, 4) void router_mfma(
    const float* __restrict__ hs,
    const float* __restrict__ noise,
    const unsigned short* __restrict__ bp,
    float* __restrict__ out_gate,
    float* __restrict__ out_idx,
    float* __restrict__ out_logits,
    int Ntok, int Hdim)
{
    __shared__ ShMem sh;

    const int tid  = threadIdx.x;
    const int lane = tid & 63;
    const int nq   = tid >> 6;           // wave = n-tile 0..7 (cols nq*16 .. nq*16+15)
    const int m0   = blockIdx.x * BM;

    const int steps = Hdim >> 5;         // 128 (even)

    f32x4 acc0 = f32x4{0.f, 0.f, 0.f, 0.f};   // rows m0+0..15
    f32x4 acc1 = f32x4{0.f, 0.f, 0.f, 0.f};   // rows m0+16..31

    // A sources: lane l covers row (l&15), k-octet (l>>4)*8.
    const float* pa0 = hs + (size_t)(m0 + (lane & 15)) * Hdim + ((lane >> 4) * 8);
    const float* pa1 = pa0 + (size_t)16 * Hdim;

    // B global base: this wave's n-tile, 3 term-frags; step s at + s*12288 ushorts.
    // Per-lane source (lane*16B) matches global_load_lds's implicit lane*16B dest.
    const unsigned short* pbw = bp + (size_t)(nq * 3) * 512 + (size_t)lane * 8;

    // Stage step s's 3 frags into ring slot (wave-uniform LDS dest). 3 vmem ops.
    #define BSTAGE(s, slot)                                                   \
        do {                                                                  \
            const unsigned short* pb = pbw + (size_t)(s) * 12288;             \
            gload_lds16(pb,        &sh.ring[nq][slot][0]);                    \
            gload_lds16(pb + 512,  &sh.ring[nq][slot][1024]);                 \
            gload_lds16(pb + 1024, &sh.ring[nq][slot][2048]);                 \
        } while (0)

    // 4 vmem ops.
    #define LOADA(d00, d01, d10, d11)                                         \
        do {                                                                  \
            d00 = *reinterpret_cast<const float4*>(pa0);                      \
            d01 = *reinterpret_cast<const float4*>(pa0 + 4);                  \
            d10 = *reinterpret_cast<const float4*>(pa1);                      \
            d11 = *reinterpret_cast<const float4*>(pa1 + 4);                  \
            pa0 += 32; pa1 += 32;                                             \
        } while (0)

    #define DSREADB(bu1, bu2, bu3, slot)                                      \
        do {                                                                  \
            const unsigned char* rb = &sh.ring[nq][slot][(int)lane * 16];     \
            bu1 = *reinterpret_cast<const ushort8*>(rb);                      \
            bu2 = *reinterpret_cast<const ushort8*>(rb + 1024);               \
            bu3 = *reinterpret_cast<const ushort8*>(rb + 2048);               \
        } while (0)

    #define SPLIT(s0, s1, A1, A2, A3)                                         \
        do {                                                                  \
            float vals[8] = {s0.x, s0.y, s0.z, s0.w, s1.x, s1.y, s1.z, s1.w}; \
            _Pragma("unroll")                                                 \
            for (int j = 0; j < 8; ++j) {                                     \
                float a  = vals[j];                                           \
                __bf16 h1 = (__bf16)a;                                        \
                float r  = a - (float)h1;                                     \
                __bf16 h2 = (__bf16)r;                                        \
                float r2 = r - (float)h2;                                     \
                __bf16 h3 = (__bf16)r2;                                       \
                A1[j] = h1; A2[j] = h2; A3[j] = h3;                           \
            }                                                                 \
        } while (0)

    #define COMPUTE(a00, a01, a10, a11, bu1, bu2, bu3)                        \
        do {                                                                  \
            bf16x8 A1a, A2a, A3a, A1b, A2b, A3b;                              \
            SPLIT(a00, a01, A1a, A2a, A3a);                                   \
            SPLIT(a10, a11, A1b, A2b, A3b);                                   \
            bf16x8 b1 = __builtin_bit_cast(bf16x8, bu1);                      \
            bf16x8 b2 = __builtin_bit_cast(bf16x8, bu2);                      \
            bf16x8 b3 = __builtin_bit_cast(bf16x8, bu3);                      \
            __builtin_amdgcn_s_setprio(1);                                    \
            acc0 = MFMA(A1a, b1, acc0);                                       \
            acc0 = MFMA(A1a, b2, acc0);                                       \
            acc0 = MFMA(A2a, b1, acc0);                                       \
            acc0 = MFMA(A2a, b2, acc0);                                       \
            acc0 = MFMA(A1a, b3, acc0);                                       \
            acc0 = MFMA(A3a, b1, acc0);                                       \
            acc1 = MFMA(A1b, b1, acc1);                                       \
            acc1 = MFMA(A1b, b2, acc1);                                       \
            acc1 = MFMA(A2b, b1, acc1);                                       \
            acc1 = MFMA(A2b, b2, acc1);                                       \
            acc1 = MFMA(A1b, b3, acc1);                                       \
            acc1 = MFMA(A3b, b1, acc1);                                       \
            __builtin_amdgcn_s_setprio(0);                                    \
        } while (0)

    // ---- prologue: B(0) -> slot 0, A(0) -> cA (order pinned: B before A) ----
    float4 cA00, cA01, cA10, cA11, nA00, nA01, nA10, nA11;
    ushort8 B1, B2, B3;

    BSTAGE(0, 0);
    SB0();                               // pin: B(0) older than A(0)
    LOADA(cA00, cA01, cA10, cA11);
    SB0();
    // invariant now: outstanding = [B(0) x3, A(0) x4]

    // ---- main loop, unroll-2 (static reg names), barrier-free ----
    for (int s = 0; s < steps; s += 2) {
        // phase 0: step s (slot 0)
        WAIT_VM4();                      // <=4 left (A(s)); B(s) landed
        DSREADB(B1, B2, B3, 0);
        WAIT_LGKM();                     // B in regs; slot 0 reusable
        BSTAGE(s + 1, 1);                // s+1 <= steps-1 always
        SB0();                           // pin: B(s+1) older than A(s+1)
        LOADA(nA00, nA01, nA10, nA11);
        SB0();
        COMPUTE(cA00, cA01, cA10, cA11, B1, B2, B3);  // compiler waits A(s)

        // phase 1: step s+1 (slot 1)
        WAIT_VM4();                      // B(s+1) landed
        DSREADB(B1, B2, B3, 1);
        WAIT_LGKM();
        if (s + 2 < steps) {
            BSTAGE(s + 2, 0);
            SB0();
            LOADA(cA00, cA01, cA10, cA11);
            SB0();
        }
        COMPUTE(nA00, nA01, nA10, nA11, B1, B2, B3);
    }

    // ---- ring no longer needed; reuse as Lred after full-block barrier ----
    __syncthreads();                     // drains all outstanding vmem/lds
    {
        int row = (lane >> 4) * 4;
        int col = nq * 16 + (lane & 15);
        #pragma unroll
        for (int r = 0; r < 4; ++r) {
            sh.Lred[row + r][col]      = acc0[r];
            sh.Lred[row + r + 16][col] = acc1[r];
        }
    }
    __syncthreads();

    // ---- per-token epilogue (proven path): one thread per token ----
    if (tid < BM) {
        const int t   = tid;
        const int tok = m0 + t;
        const float* nrow = noise + (size_t)tok * EE;
        float* lrow = out_logits + (size_t)tok * EE;

        float m = -3.4e38f;
        for (int e = 0; e < EE; ++e) {
            float gv = sh.Lred[t][e];
            float nv = sh.Lred[t][EE + e];
            float sp = fmaxf(nv, 0.f) + log1pf(expf(-fabsf(nv)));  // stable softplus
            float l  = fmaf(nrow[e], sp, gv);                      // NOISE_STD = 1
            lrow[e]  = l;
            sh.Lred[t][e] = l;
            m = fmaxf(m, l);
        }

        float Z = 0.f;
        float p1 = -1.f, p2 = -1.f;
        int   i1 = 0,    i2 = 0;
        for (int e = 0; e < EE; ++e) {
            float p = expf(sh.Lred[t][e] - m);
            Z += p;
            if (p > p1)      { p2 = p1; i2 = i1; p1 = p; i1 = e; }  // ties -> lower idx
            else if (p > p2) { p2 = p;  i2 = e; }
        }
        float q1 = p1 / Z, q2 = p2 / Z;
        float denom = q1 + q2 + 1e-9f;
        float w1 = q1 / denom, w2 = q2 / denom;

        out_idx[(size_t)tok * 2 + 0] = (float)i1;
        out_idx[(size_t)tok * 2 + 1] = (float)i2;

        float* grow = out_gate + (size_t)tok * EE;
        for (int e = 0; e < EE; ++e)
            grow[e] = (e == i1) ? w1 : ((e == i2) ? w2 : 0.f);
    }
}

extern "C" void kernel_launch(void* const* d_in, const int* in_sizes, int n_in,
                              void* d_out, int out_size, void* d_ws, size_t ws_size,
                              hipStream_t stream) {
    const float* hs    = (const float*)d_in[0];
    const float* noise = (const float*)d_in[1];
    const float* wg    = (const float*)d_in[2];
    const float* wn    = (const float*)d_in[3];

    const int Ntok = in_sizes[1] / EE;    // noise is [N][64]
    const int Hdim = in_sizes[2] / EE;    // w_gate is [64][H]

    float* out_gate   = (float*)d_out;
    float* out_idx    = out_gate + (size_t)Ntok * EE;
    float* out_logits = out_idx  + (size_t)Ntok * 2;

    unsigned short* bp = (unsigned short*)d_ws;   // needs (H/32)*8*3*512*2 = 3 MB

    // pack W into MFMA B-fragment layout (3 bf16 terms)
    int pairs = (Hdim / 32) * 8;
    hipLaunchKernelGGL(pack_b, dim3(pairs / 4), dim3(256), 0, stream, wg, wn, bp, Hdim);

    hipLaunchKernelGGL(router_mfma, dim3(Ntok / BM), dim3(512), 0, stream,
                       hs, noise, bp, out_gate, out_idx, out_logits, Ntok, Hdim);
}

// Round 14
// 290.235 us; speedup vs baseline: 1.1459x; 1.1459x over previous
//
#include <hip/hip_runtime.h>
#include <math.h>

// NoisyTopKRouter, round 14: amortize B latency via MT=4 (24 MFMA per 3-load cluster).
//   Corrected r9 reading: diag's B was loop-invariant (hoisted) -> 60us proves
//   "B-in-regs = near-roofline". Compiler defeats forced prefetch (r10-r13).
//   So: raise MFMA:B-cluster ratio instead. 8 waves = 8 n-tiles, MT=4 m-tiles/wave,
//   BM=64, grid 256, full K per wave (no reduction), barrier-free, JIT B loads
//   (B first, SPLIT VALU overlaps the latency), parity-named A double-buffer.
// Outputs (flat f32): gate_weights [N][64], top2 idx as float [N][2], logits [N][64].

typedef float   f32x4   __attribute__((ext_vector_type(4)));
typedef __bf16  bf16x8  __attribute__((ext_vector_type(8)));
typedef unsigned short ushort8 __attribute__((ext_vector_type(8)));

#define EE 64     // experts
#define E2 128    // gate+noise logit columns
#define BM 64     // tokens per block
#define MT 4      // m-tiles per wave

__device__ __forceinline__ unsigned short bf16_rne(float f) {
    unsigned int u = __float_as_uint(f);
    u += 0x7fffu + ((u >> 16) & 1u);
    return (unsigned short)(u >> 16);
}
__device__ __forceinline__ float bf16_f32(unsigned short h) {
    return __uint_as_float(((unsigned int)h) << 16);
}
__device__ __forceinline__ void split3(float a, unsigned short& h1,
                                       unsigned short& h2, unsigned short& h3) {
    h1 = bf16_rne(a);
    float r  = a - bf16_f32(h1);     // exact
    h2 = bf16_rne(r);
    float r2 = r - bf16_f32(h2);     // exact
    h3 = bf16_rne(r2);
}

// ---- pre-kernel: pack W (gate cols 0..63, noise cols 64..127) into B-frag order.
// Fragment (16x16x32 bf16, verified): lane l holds col=l&15, k=(l>>4)*8+j.
// Packed ushort addr: ((ks*8 + nt)*3 + term)*512 + lane*8 + j   (ks = k/32)
__global__ __launch_bounds__(256) void pack_b(
    const float* __restrict__ wg, const float* __restrict__ wn,
    unsigned short* __restrict__ bp, int Hdim)
{
    int pair = blockIdx.x * 4 + (threadIdx.x >> 6);   // (ks, nt)
    int l    = threadIdx.x & 63;
    int ks   = pair >> 3;
    int nt   = pair & 7;
    int col  = nt * 16 + (l & 15);
    int k    = ks * 32 + ((l >> 4) * 8);
    const float* wrow = (col < EE) ? (wg + (size_t)col * Hdim)
                                   : (wn + (size_t)(col - EE) * Hdim);
    float4 v0 = *reinterpret_cast<const float4*>(wrow + k);
    float4 v1 = *reinterpret_cast<const float4*>(wrow + k + 4);
    float vals[8] = {v0.x, v0.y, v0.z, v0.w, v1.x, v1.y, v1.z, v1.w};
    ushort8 t1, t2, t3;
    #pragma unroll
    for (int j = 0; j < 8; ++j) {
        unsigned short a, b, c;
        split3(vals[j], a, b, c);
        t1[j] = a; t2[j] = b; t3[j] = c;
    }
    size_t base = ((size_t)(ks * 8 + nt) * 3) * 512 + (size_t)l * 8;
    *reinterpret_cast<ushort8*>(bp + base        ) = t1;
    *reinterpret_cast<ushort8*>(bp + base + 512  ) = t2;
    *reinterpret_cast<ushort8*>(bp + base + 1024 ) = t3;
}

#define MFMA(a, b, c) __builtin_amdgcn_mfma_f32_16x16x32_bf16((a), (b), (c), 0, 0, 0)

__global__ __launch_bounds__(512, 2) void router_mfma(
    const float* __restrict__ hs,
    const float* __restrict__ noise,
    const unsigned short* __restrict__ bp,
    float* __restrict__ out_gate,
    float* __restrict__ out_idx,
    float* __restrict__ out_logits,
    int Ntok, int Hdim)
{
    __shared__ float Lred[BM][E2 + 5];   // stride 133 -> conflict-free scalar reads

    const int tid  = threadIdx.x;
    const int lane = tid & 63;
    const int nq   = tid >> 6;           // wave = n-tile 0..7 (cols nq*16..nq*16+15)
    const int m0   = blockIdx.x * BM;

    const int steps = Hdim >> 5;         // 128 (even)

    f32x4 acc[MT];
    #pragma unroll
    for (int mt = 0; mt < MT; ++mt) acc[mt] = f32x4{0.f, 0.f, 0.f, 0.f};

    // A sources: lane l covers row (l&15) of m-tile mt, k-octet (l>>4)*8.
    const float* pa[MT];
    #pragma unroll
    for (int mt = 0; mt < MT; ++mt)
        pa[mt] = hs + (size_t)(m0 + mt * 16 + (lane & 15)) * Hdim + ((lane >> 4) * 8);

    // B base: this wave's n-tile (3 term-frags); step s at + s*12288 ushorts.
    const unsigned short* pbw = bp + (size_t)(nq * 3) * 512 + (size_t)lane * 8;

    #define LOADA(d0, d1)                                                     \
        do {                                                                  \
            _Pragma("unroll")                                                 \
            for (int mt = 0; mt < MT; ++mt) {                                 \
                d0[mt] = *reinterpret_cast<const float4*>(pa[mt]);            \
                d1[mt] = *reinterpret_cast<const float4*>(pa[mt] + 4);        \
                pa[mt] += 32;                                                 \
            }                                                                 \
        } while (0)

    // COMPUTE: issue the 3 B loads FIRST (JIT), overlap their latency with the
    // 4 SPLITs (~160 VALU cyc), then 24 dense MFMAs.
    #define COMPUTE(s, s0, s1)                                                \
        do {                                                                  \
            const unsigned short* pb = pbw + (size_t)(s) * 12288;             \
            ushort8 bu1 = *reinterpret_cast<const ushort8*>(pb);              \
            ushort8 bu2 = *reinterpret_cast<const ushort8*>(pb + 512);        \
            ushort8 bu3 = *reinterpret_cast<const ushort8*>(pb + 1024);       \
            bf16x8 A1[MT], A2[MT], A3[MT];                                    \
            _Pragma("unroll")                                                 \
            for (int mt = 0; mt < MT; ++mt) {                                 \
                float vals[8] = {s0[mt].x, s0[mt].y, s0[mt].z, s0[mt].w,      \
                                 s1[mt].x, s1[mt].y, s1[mt].z, s1[mt].w};     \
                _Pragma("unroll")                                             \
                for (int j = 0; j < 8; ++j) {                                 \
                    float a  = vals[j];                                       \
                    __bf16 h1 = (__bf16)a;                                    \
                    float r  = a - (float)h1;                                 \
                    __bf16 h2 = (__bf16)r;                                    \
                    float r2 = r - (float)h2;                                 \
                    __bf16 h3 = (__bf16)r2;                                   \
                    A1[mt][j] = h1; A2[mt][j] = h2; A3[mt][j] = h3;           \
                }                                                             \
            }                                                                 \
            bf16x8 b1 = __builtin_bit_cast(bf16x8, bu1);                      \
            bf16x8 b2 = __builtin_bit_cast(bf16x8, bu2);                      \
            bf16x8 b3 = __builtin_bit_cast(bf16x8, bu3);                      \
            __builtin_amdgcn_s_setprio(1);                                    \
            _Pragma("unroll")                                                 \
            for (int mt = 0; mt < MT; ++mt) {                                 \
                acc[mt] = MFMA(A1[mt], b1, acc[mt]);                          \
                acc[mt] = MFMA(A1[mt], b2, acc[mt]);                          \
                acc[mt] = MFMA(A2[mt], b1, acc[mt]);                          \
                acc[mt] = MFMA(A2[mt], b2, acc[mt]);                          \
                acc[mt] = MFMA(A1[mt], b3, acc[mt]);                          \
                acc[mt] = MFMA(A3[mt], b1, acc[mt]);                          \
            }                                                                 \
            __builtin_amdgcn_s_setprio(0);                                    \
        } while (0)

    // ---- barrier-free main loop; A parity double-buffered (named reg sets) ----
    float4 c0[MT], c1[MT], n0[MT], n1[MT];
    LOADA(c0, c1);                        // A(0)
    for (int s = 0; s < steps; s += 2) {
        LOADA(n0, n1);                    // A(s+1)
        COMPUTE(s, c0, c1);
        if (s + 2 < steps) LOADA(c0, c1); // A(s+2)
        COMPUTE(s + 1, n0, n1);
    }

    // ---- write logits (each wave owns disjoint 16 cols; no reduction) ----
    // C/D frag (verified): reg r -> row=(lane>>4)*4+r, col=lane&15.
    {
        int row = (lane >> 4) * 4;
        int col = nq * 16 + (lane & 15);
        #pragma unroll
        for (int mt = 0; mt < MT; ++mt)
            #pragma unroll
            for (int r = 0; r < 4; ++r)
                Lred[mt * 16 + row + r][col] = acc[mt][r];
    }
    __syncthreads();

    // ---- per-token epilogue (proven path): one thread per token (wave 0) ----
    if (tid < BM) {
        const int t   = tid;
        const int tok = m0 + t;
        const float* nrow = noise + (size_t)tok * EE;
        float* lrow = out_logits + (size_t)tok * EE;

        float m = -3.4e38f;
        for (int e = 0; e < EE; ++e) {
            float gv = Lred[t][e];
            float nv = Lred[t][EE + e];
            float sp = fmaxf(nv, 0.f) + log1pf(expf(-fabsf(nv)));  // stable softplus
            float l  = fmaf(nrow[e], sp, gv);                      // NOISE_STD = 1
            lrow[e]  = l;
            Lred[t][e] = l;
            m = fmaxf(m, l);
        }

        float Z = 0.f;
        float p1 = -1.f, p2 = -1.f;
        int   i1 = 0,    i2 = 0;
        for (int e = 0; e < EE; ++e) {
            float p = expf(Lred[t][e] - m);
            Z += p;
            if (p > p1)      { p2 = p1; i2 = i1; p1 = p; i1 = e; }  // ties -> lower idx
            else if (p > p2) { p2 = p;  i2 = e; }
        }
        float q1 = p1 / Z, q2 = p2 / Z;
        float denom = q1 + q2 + 1e-9f;
        float w1 = q1 / denom, w2 = q2 / denom;

        out_idx[(size_t)tok * 2 + 0] = (float)i1;
        out_idx[(size_t)tok * 2 + 1] = (float)i2;

        float* grow = out_gate + (size_t)tok * EE;
        for (int e = 0; e < EE; ++e)
            grow[e] = (e == i1) ? w1 : ((e == i2) ? w2 : 0.f);
    }
}

extern "C" void kernel_launch(void* const* d_in, const int* in_sizes, int n_in,
                              void* d_out, int out_size, void* d_ws, size_t ws_size,
                              hipStream_t stream) {
    const float* hs    = (const float*)d_in[0];
    const float* noise = (const float*)d_in[1];
    const float* wg    = (const float*)d_in[2];
    const float* wn    = (const float*)d_in[3];

    const int Ntok = in_sizes[1] / EE;    // noise is [N][64]
    const int Hdim = in_sizes[2] / EE;    // w_gate is [64][H]

    float* out_gate   = (float*)d_out;
    float* out_idx    = out_gate + (size_t)Ntok * EE;
    float* out_logits = out_idx  + (size_t)Ntok * 2;

    unsigned short* bp = (unsigned short*)d_ws;   // needs (H/32)*8*3*512*2 = 3 MB

    // pack W into MFMA B-fragment layout (3 bf16 terms)
    int pairs = (Hdim / 32) * 8;
    hipLaunchKernelGGL(pack_b, dim3(pairs / 4), dim3(256), 0, stream, wg, wn, bp, Hdim);

    hipLaunchKernelGGL(router_mfma, dim3(Ntok / BM), dim3(512), 0, stream,
                       hs, noise, bp, out_gate, out_idx, out_logits, Ntok, Hdim);
}